// Round 3
// baseline (349.098 us; speedup 1.0000x reference)
//
#include <hip/hip_runtime.h>

#define N_T 8
#define N_CAPS 16
#define CAP_DIM 16
#define HW 4096
#define PT 256            // positions per tile: 1 KiB per channel -> one wave instr
#define NT 4              // consecutive tiles per block (persistent)
#define EPS 1e-6f

// Block: 512 threads (8 waves), one (b, capsule c) pair x 4 tiles of 256 positions.
// KEY CHANGE vs rounds 0-2: every global load/store instruction is a single
// contiguous 1 KiB run (64 lanes x float4 within ONE channel), matching the
// pattern that reaches 6.3 TB/s in the copy microbench, instead of 4 scattered
// 256B chunks at 16 KiB stride.
// LDS: u^2 tile 128 ch x 256 pos x 4B = 128 KiB (gfx950 WG limit 160 KiB).
// Pipeline: u for tile i+1 is reg-staged while tile i computes.
__global__ __launch_bounds__(512, 2) void caps_norm_kernel(
    const float* __restrict__ z, const float* __restrict__ u,
    const float* __restrict__ w, const float* __restrict__ beta,
    float* __restrict__ out)
{
    __shared__ float lds[128 * PT];       // 128 KiB

    const int tid = threadIdx.x;
    const int bid = blockIdx.x;           // ((b*16 + c)*4 + pg)
    const int pg  = bid & 3;
    const int c   = (bid >> 2) & 15;
    const int b   = bid >> 6;
    const int pbase = pg * (PT * NT);     // 1024 positions per block

    float W9[9];
#pragma unroll
    for (int i = 0; i < 9; ++i) W9[i] = w[i];
    const float bet = beta[0];

    const size_t base_b = (size_t)b * 2048 * HW;
    const float* ub = u + base_b;
    const float* zb = z + base_b;
    float*       ob = out + base_b;

    const int wv = tid >> 6;              // wave id 0..7
    const int q  = tid & 63;              // lane = float4 slot within a 256-pos row

    // Per-wave instruction k: row r = wv + 8k (wave-uniform), lanes cover the
    // whole 1 KiB row -> fully contiguous global & LDS access.
    int OFF[16];                          // element offset: ch*HW + q*4
#pragma unroll
    for (int k = 0; k < 16; ++k) {
        int r = wv + (k << 3);            // channel row 0..127 (= t*16 + d)
        int t = r >> 4, d = r & 15;
        OFF[k] = (t * 256 + c * 16 + d) * HW + (q << 2);
    }

    float4 uA[16], uB[16];

#define STAGE_U(TI, UR)                                                      \
    {                                                                        \
        const int p0_ = pbase + (TI) * PT;                                   \
        _Pragma("unroll")                                                    \
        for (int k = 0; k < 16; ++k)                                         \
            UR[k] = *(const float4*)(ub + OFF[k] + p0_);                     \
    }

#define SQW(UR)                                                              \
    {                                                                        \
        _Pragma("unroll")                                                    \
        for (int k = 0; k < 16; ++k) {                                       \
            float4 v = UR[k];                                                \
            float4 sq;                                                       \
            sq.x = v.x*v.x; sq.y = v.y*v.y; sq.z = v.z*v.z; sq.w = v.w*v.w;  \
            *(float4*)(&lds[((wv + (k << 3)) << 8) + (q << 2)]) = sq;        \
        }                                                                    \
    }

#define COMP(TI)                                                             \
    {                                                                        \
        const int p0_ = pbase + (TI) * PT;                                   \
        _Pragma("unroll")                                                    \
        for (int k = 0; k < 16; ++k) {                                       \
            int r = wv + (k << 3);                                           \
            int t = r >> 4, d = r & 15;                                      \
            float ax = 0.f, ay = 0.f, az = 0.f, aw = 0.f;                    \
            _Pragma("unroll")                                                \
            for (int i = 0; i < 3; ++i) {                                    \
                int tt = (t + i + 7) & 7;                                    \
                _Pragma("unroll")                                            \
                for (int j = 0; j < 3; ++j) {                                \
                    int dd = (d + j + 15) & 15;                              \
                    float ww = W9[i * 3 + j];                                \
                    const float4 a = *(const float4*)(                       \
                        &lds[(((tt << 4) + dd) << 8) + (q << 2)]);           \
                    ax += ww*a.x; ay += ww*a.y; az += ww*a.z; aw += ww*a.w;  \
                }                                                            \
            }                                                                \
            const float4 z4 = *(const float4*)(zb + OFF[k] + p0_);           \
            float4 o;                                                        \
            o.x = (z4.x + bet) * rsqrtf(ax + EPS);                           \
            o.y = (z4.y + bet) * rsqrtf(ay + EPS);                           \
            o.z = (z4.z + bet) * rsqrtf(az + EPS);                           \
            o.w = (z4.w + bet) * rsqrtf(aw + EPS);                           \
            *(float4*)(ob + OFF[k] + p0_) = o;                               \
        }                                                                    \
    }

    // ---- pipeline over 4 consecutive tiles (single LDS buffer, reg dbuf) ----
    STAGE_U(0, uA)
    SQW(uA)
    __syncthreads();

    STAGE_U(1, uB)                        // next-tile u loads in flight...
    COMP(0)                               // ...while computing current tile
    __syncthreads();                      // all lds reads done
    SQW(uB)
    __syncthreads();                      // lds holds tile 1

    STAGE_U(2, uA)
    COMP(1)
    __syncthreads();
    SQW(uA)
    __syncthreads();

    STAGE_U(3, uB)
    COMP(2)
    __syncthreads();
    SQW(uB)
    __syncthreads();

    COMP(3)                               // drain

#undef STAGE_U
#undef SQW
#undef COMP
}

extern "C" void kernel_launch(void* const* d_in, const int* in_sizes, int n_in,
                              void* d_out, int out_size, void* d_ws, size_t ws_size,
                              hipStream_t stream) {
    const float* z    = (const float*)d_in[0];
    const float* u    = (const float*)d_in[1];
    const float* w    = (const float*)d_in[2];
    const float* beta = (const float*)d_in[3];
    float* out = (float*)d_out;

    // grid = B(4) * N_CAPS(16) * (HW / (PT*NT) = 4) = 256 blocks
    caps_norm_kernel<<<dim3(256), dim3(512), 0, stream>>>(z, u, w, beta, out);
}

// Round 4
// 338.389 us; speedup vs baseline: 1.0316x; 1.0316x over previous
//
#include <hip/hip_runtime.h>

#define HW 4096
#define PT 256          // positions per tile: each LDS row = 1 KiB
#define NT 4            // tiles per block
#define EPS 1e-6f

// Block: 512 threads (8 waves), one (b, capsule c) x 4 tiles of 256 positions.
// u is read in FULL 1 KiB contiguous runs per wave instruction (row-uniform),
// squared in registers, written to LDS with the contiguous-write shape that
// measured 0 conflicts in R2. The stencil reads use R2's proven-free
// 4-rows x 16-quads shape. Register staging keeps next-tile u loads in
// flight through the current tile's compute (1 block/CU is fine: R2 showed
// occupancy is not the lever, pipelining keeps HBM busy).
__global__ __launch_bounds__(512, 1) void caps_norm_kernel(
    const float* __restrict__ z, const float* __restrict__ u,
    const float* __restrict__ w, const float* __restrict__ beta,
    float* __restrict__ out)
{
    __shared__ float lds[128 * PT];       // 128 KiB, u^2, row-major [128][256]

    const int tid = threadIdx.x;
    const int wv  = tid >> 6;             // wave 0..7
    const int ln  = tid & 63;             // lane
    const int bid = blockIdx.x;           // ((b*16+c)*4 + pg)
    const int pg  = bid & 3;
    const int c   = (bid >> 2) & 15;
    const int b   = bid >> 6;
    const int pblk = pg * (PT * NT);      // 1024 positions per block

    float W9[9];
#pragma unroll
    for (int i = 0; i < 9; ++i) W9[i] = w[i];
    const float bet = beta[0];

    const size_t base_b = (size_t)b * 2048 * HW;
    const float* ub = u + base_b;
    const float* zb = z + base_b;
    float*       ob = out + base_b;

    float4 uS[16];                        // staged raw u, next tile (64 VGPR)

    // STAGE: instr k reads row r = wv*16+k, lanes cover the full 1 KiB row
    // -> one contiguous 1 KiB global read per wave instruction.
#define STAGE(T)                                                              \
    {                                                                         \
        const int p0_ = pblk + (T) * PT;                                      \
        _Pragma("unroll")                                                     \
        for (int k = 0; k < 16; ++k) {                                        \
            const int r = wv * 16 + k;                                        \
            const int ch = (r >> 4) * 256 + c * 16 + (r & 15);                \
            uS[k] = *(const float4*)(ub + (size_t)ch * HW + p0_ + ln * 4);    \
        }                                                                     \
    }

    // SQWRITE: square in regs, contiguous 1 KiB LDS write per wave instr
    // (shape measured conflict-free in R2).
#define SQWRITE()                                                             \
    {                                                                         \
        _Pragma("unroll")                                                     \
        for (int k = 0; k < 16; ++k) {                                        \
            const int r = wv * 16 + k;                                        \
            const float4 v = uS[k];                                           \
            float4 s4;                                                        \
            s4.x = v.x*v.x; s4.y = v.y*v.y; s4.z = v.z*v.z; s4.w = v.w*v.w;   \
            *(float4*)(&lds[r * PT + ln * 4]) = s4;                           \
        }                                                                     \
    }

    // COMP: slot k = (k&3)=quad-group, (k>>2)=row-group-index.
    // Per instr: 4 consecutive rows x 16 consecutive quads (R2's proven
    // conflict-free stencil-read shape). z/out ride the same lanes
    // (4 x 256 B granules at 16 KiB stride, R0-proven pattern).
#define COMP(T)                                                               \
    {                                                                         \
        const int p0_ = pblk + (T) * PT;                                      \
        _Pragma("unroll")                                                     \
        for (int k = 0; k < 16; ++k) {                                        \
            const int r = (wv + 8 * (k >> 2)) * 4 + (ln >> 4);                \
            const int q = (k & 3) * 16 + (ln & 15);                           \
            const int t = r >> 4, d = r & 15;                                 \
            const int ch = t * 256 + c * 16 + d;                              \
            const size_t g = (size_t)ch * HW + p0_ + q * 4;                   \
            const float4 z4 = *(const float4*)(zb + g);                       \
            float ax = 0.f, ay = 0.f, az_ = 0.f, aw = 0.f;                    \
            _Pragma("unroll")                                                 \
            for (int i = 0; i < 3; ++i) {                                     \
                const int tt = (t + i + 7) & 7;                               \
                _Pragma("unroll")                                             \
                for (int j = 0; j < 3; ++j) {                                 \
                    const int dd = (d + j + 15) & 15;                         \
                    const float ww = W9[i * 3 + j];                           \
                    const float4 a = *(const float4*)(                        \
                        &lds[((tt << 4) + dd) * PT + q * 4]);                 \
                    ax += ww*a.x; ay += ww*a.y; az_ += ww*a.z; aw += ww*a.w;  \
                }                                                             \
            }                                                                 \
            float4 o;                                                         \
            o.x = (z4.x + bet) * rsqrtf(ax + EPS);                            \
            o.y = (z4.y + bet) * rsqrtf(ay + EPS);                            \
            o.z = (z4.z + bet) * rsqrtf(az_ + EPS);                           \
            o.w = (z4.w + bet) * rsqrtf(aw + EPS);                            \
            *(float4*)(ob + g) = o;                                           \
        }                                                                     \
    }

    // ---- pipeline: STAGE(t+1) loads fly through COMP(t) ----
    STAGE(0)
    SQWRITE()                              // waits vmcnt for tile0, u^2 -> LDS
    STAGE(1)                               // tile1 loads in flight
    __syncthreads();                       // LDS(tile0) visible

    COMP(0)
    __syncthreads();                       // stencil reads of tile0 done
    SQWRITE()                              // tile1 -> LDS (uS free after)
    STAGE(2)                               // tile2 loads fly through COMP(1)
    __syncthreads();

    COMP(1)
    __syncthreads();
    SQWRITE()
    STAGE(3)
    __syncthreads();

    COMP(2)
    __syncthreads();
    SQWRITE()
    __syncthreads();

    COMP(3)                                // drain

#undef STAGE
#undef SQWRITE
#undef COMP
}

extern "C" void kernel_launch(void* const* d_in, const int* in_sizes, int n_in,
                              void* d_out, int out_size, void* d_ws, size_t ws_size,
                              hipStream_t stream) {
    const float* z    = (const float*)d_in[0];
    const float* u    = (const float*)d_in[1];
    const float* w    = (const float*)d_in[2];
    const float* beta = (const float*)d_in[3];
    float* out = (float*)d_out;

    // grid = B(4) * N_CAPS(16) * (HW / (PT*NT) = 4) = 256 blocks, 1/CU
    caps_norm_kernel<<<dim3(256), dim3(512), 0, stream>>>(z, u, w, beta, out);
}